// Round 15
// baseline (115.607 us; speedup 1.0000x reference)
//
#include <hip/hip_runtime.h>
#include <math.h>

#define N_FFT 16384
#define HALF 8192
#define ROWS 1024    // B*Cin = B*Cout = 16*64
#define KS_A 128     // k-splits of the 8192 half-space
#define KR_A 64      // half-k per kA block
#define CHUNK 32     // half-k per LDS stage
#define NMASK 16383

// ---------------- ws layout (float offsets) ----------------
// castab @0      [16384]   cas(2*pi*i/N)
// costab @16384  [16384]   2*cos(2*pi*i/N)
// partial@32768  [128*65536]
// xh     @8421376 [65536]
// lowT   @8486912 [65536]

__global__ __launch_bounds__(256) void k_tab(float* __restrict__ castab,
                                             float* __restrict__ costab) {
    int i = blockIdx.x * 256 + threadIdx.x;   // grid 64*256 = 16384 exactly
    double ang = 6.283185307179586476925287 * (double)i / (double)N_FFT;
    double c = cos(ang), s = sin(ang);
    castab[i] = (float)(c + s);
    costab[i] = (float)(2.0 * c);
}

// Step A (half-symmetric + cas recurrence):
//   partial[ks][r][c] = sum_{k in split} (x[r][k] +- x[r][k+8192]) * cas(k*m_c*theta)
// grid 1024 = 8 rb * 128 ks (4 blocks/CU); block 512 = 8 waves;
// wave = 8 m-cols (single parity), lane = 2 rows. 2 chunks per block.
__global__ __launch_bounds__(512, 8) void kA(const float* __restrict__ x,
                                             const float* __restrict__ castab,
                                             const float* __restrict__ costab,
                                             float* __restrict__ partial) {
    const int rb = blockIdx.x & 7;
    const int ks = blockIdx.x >> 3;
    const int rowbase = rb << 7;
    const int kbase = ks * KR_A;

    __shared__ float xs[CHUNK][2][128];   // [k][parity][row-swizzled], 32 KB

    const int t   = threadIdx.x;
    const int wq  = __builtin_amdgcn_readfirstlane(t >> 6);  // 0..7, uniform
    const int lam = t & 63;
    const int c0  = wq * 8;               // permuted col octet (single parity)
    const int p   = wq >> 2;              // 0: even m (sum), 1: odd m (diff)
    const int r2  = lam * 2;              // local row pair
    const int mbase = (wq < 4) ? (wq << 4) : (((wq - 4) << 4) + 1);

    float k2[8], cA[8], cB[8];
#pragma unroll
    for (int j = 0; j < 8; ++j) {
        const int m = mbase + 2 * j;
        k2[j] = costab[m];                              // 2*cos(m*theta)
        cB[j] = castab[((kbase - 1) * m) & NMASK];      // cas((kbase-1)*m)
        cA[j] = castab[(kbase * m) & NMASK];            // cas(kbase*m)
    }

    float acc0[8], acc1[8];
#pragma unroll
    for (int j = 0; j < 8; ++j) { acc0[j] = 0.f; acc1[j] = 0.f; }

    for (int ch = 0; ch < KR_A / CHUNK; ++ch) {
        const int k0 = kbase + ch * CHUNK;
        if (ch) __syncthreads();
        // stage halfsums: 128 rows x 32 k
#pragma unroll
        for (int it = 0; it < 2; ++it) {
            const int idx = it * 512 + t;
            const int r = idx >> 3, kq = idx & 7;
            const float4 a4 = *reinterpret_cast<const float4*>(
                &x[(size_t)(rowbase + r) * N_FFT + k0 + kq * 4]);
            const float4 b4 = *reinterpret_cast<const float4*>(
                &x[(size_t)(rowbase + r) * N_FFT + k0 + kq * 4 + HALF]);
            const int rsw = r ^ (kq << 1);
#pragma unroll
            for (int u = 0; u < 4; ++u) {
                const float a = reinterpret_cast<const float*>(&a4)[u];
                const float b = reinterpret_cast<const float*>(&b4)[u];
                xs[kq * 4 + u][0][rsw] = a + b;
                xs[kq * 4 + u][1][rsw] = a - b;
            }
        }
        __syncthreads();

        for (int k = 0; k < CHUNK; k += 2) {
            {   // step k: current = cA; then cB <- c_{k+1}
                const int rd = r2 ^ ((k >> 2) << 1);
                const float2 s2 = *reinterpret_cast<const float2*>(&xs[k][p][rd]);
#pragma unroll
                for (int j = 0; j < 8; ++j) {
                    acc0[j] = fmaf(s2.x, cA[j], acc0[j]);
                    acc1[j] = fmaf(s2.y, cA[j], acc1[j]);
                    cB[j] = fmaf(k2[j], cA[j], -cB[j]);
                }
            }
            {   // step k+1: current = cB; then cA <- c_{k+2}
                const int rd = r2 ^ (((k + 1) >> 2) << 1);
                const float2 s2 = *reinterpret_cast<const float2*>(&xs[k + 1][p][rd]);
#pragma unroll
                for (int j = 0; j < 8; ++j) {
                    acc0[j] = fmaf(s2.x, cB[j], acc0[j]);
                    acc1[j] = fmaf(s2.y, cB[j], acc1[j]);
                    cA[j] = fmaf(k2[j], cB[j], -cA[j]);
                }
            }
        }
    }

#pragma unroll
    for (int i = 0; i < 2; ++i) {
        float* pp = &partial[((size_t)ks << 16) +
                             (size_t)(rowbase + r2 + i) * 64 + c0];
        const float* a = i ? acc1 : acc0;
        *reinterpret_cast<float4*>(pp) =
            make_float4(a[0], a[1], a[2], a[3]);
        *reinterpret_cast<float4*>(pp + 4) =
            make_float4(a[4], a[5], a[6], a[7]);
    }
}

// reduce KS_A=128 partials -> xh (un-permuting columns)
// grid 1024 x 256: block = 64 idx x 4 sp-groups (32 sp each); LDS reduce.
__global__ __launch_bounds__(256) void kR(const float* __restrict__ partial,
                                          float* __restrict__ xh) {
    const int lane = threadIdx.x & 63;
    const int sg   = threadIdx.x >> 6;              // 0..3
    const int idx  = blockIdx.x * 64 + lane;        // 0..65535
    const int sp0  = sg << 5;                       // 32 sp per group

    float a0 = 0.f, a1 = 0.f, a2 = 0.f, a3 = 0.f;
#pragma unroll
    for (int i = 0; i < 32; i += 4) {
        a0 += partial[((size_t)(sp0 + i + 0) << 16) + idx];
        a1 += partial[((size_t)(sp0 + i + 1) << 16) + idx];
        a2 += partial[((size_t)(sp0 + i + 2) << 16) + idx];
        a3 += partial[((size_t)(sp0 + i + 3) << 16) + idx];
    }
    const float s = (a0 + a1) + (a2 + a3);

    __shared__ float red[4][64];
    red[sg][lane] = s;
    __syncthreads();
    if (sg == 0) {
        const float v = (red[0][lane] + red[1][lane]) +
                        (red[2][lane] + red[3][lane]);
        const int r = idx >> 6, c = idx & 63;
        const int m = (c < 32) ? (2 * c) : (2 * (c - 32) + 1);
        xh[(r << 6) + m] = v;
    }
}

// Step B: lowT[m][b*64+o] = (1/N) * sum_i xh[b*64+i][m] * w[(o*64+i)*64+m]
// grid 256 = 16 b * 16 og; block 256 = 4 o * 64 m.
__global__ __launch_bounds__(256) void kB(const float* __restrict__ xh,
                                          const float* __restrict__ w,
                                          float* __restrict__ lowT) {
    const int b  = blockIdx.x >> 4;
    const int og = blockIdx.x & 15;
    const int o  = og * 4 + (threadIdx.x >> 6);
    const int m  = threadIdx.x & 63;
    float a0 = 0.f, a1 = 0.f, a2 = 0.f, a3 = 0.f;
#pragma unroll 4
    for (int i = 0; i < 64; i += 4) {
        a0 = fmaf(xh[(size_t)((b * 64 + i + 0) << 6) + m], w[(size_t)((o * 64 + i + 0) << 6) + m], a0);
        a1 = fmaf(xh[(size_t)((b * 64 + i + 1) << 6) + m], w[(size_t)((o * 64 + i + 1) << 6) + m], a1);
        a2 = fmaf(xh[(size_t)((b * 64 + i + 2) << 6) + m], w[(size_t)((o * 64 + i + 2) << 6) + m], a2);
        a3 = fmaf(xh[(size_t)((b * 64 + i + 3) << 6) + m], w[(size_t)((o * 64 + i + 3) << 6) + m], a3);
    }
    lowT[(size_t)m * ROWS + b * 64 + o] = ((a0 + a1) + (a2 + a3)) * (1.0f / (float)N_FFT);
}

// Step C (half-symmetric + cas recurrence, LDS-broadcast lowT):
//   out[r][n] = Se+So, out[r][n+8192] = Se-So (n<8192)
// grid 2048 = 64 rb * 32 nb; block 256 = 4 waves; tile 16 rows x 256 n.
__global__ __launch_bounds__(256, 4) void kC(const float* __restrict__ lowT,
                                             const float* __restrict__ castab,
                                             const float* __restrict__ costab,
                                             float* __restrict__ out) {
    const int rb = blockIdx.x >> 5;
    const int nb = blockIdx.x & 31;
    const int rowbase = rb << 4;          // 16 rows
    const int n0 = nb << 8;               // 256 half-n

    __shared__ float ls[64][16];          // [m][r], 4 KB

    const int t  = threadIdx.x;
    const int rg = __builtin_amdgcn_readfirstlane(t >> 6);   // 0..3, uniform
    const int nl = t & 63;
    const int n  = n0 + nl * 4;           // lane's 4 n: n..n+3

    // stage lowT tile: 1024 floats
#pragma unroll
    for (int it = 0; it < 4; ++it) {
        const int f = it * 256 + t;
        const int m = f >> 4, r = f & 15;
        ls[m][r] = lowT[((size_t)m << 10) + rowbase + r];
    }
    __syncthreads();

    float k2[4], ce[4], co[4];
#pragma unroll
    for (int j = 0; j < 4; ++j) {
        k2[j] = costab[n + j];
        ce[j] = 1.0f;
        co[j] = castab[n + j];
    }

    float se[4][4], so[4][4];
#pragma unroll
    for (int r = 0; r < 4; ++r)
#pragma unroll
        for (int j = 0; j < 4; ++j) { se[r][j] = 0.f; so[r][j] = 0.f; }

#pragma unroll 4
    for (int g = 0; g < 32; ++g) {
        const float4 le = *reinterpret_cast<const float4*>(&ls[2 * g][rg * 4]);
        const float4 lo = *reinterpret_cast<const float4*>(&ls[2 * g + 1][rg * 4]);
        const float lev[4] = {le.x, le.y, le.z, le.w};
        const float lov[4] = {lo.x, lo.y, lo.z, lo.w};
#pragma unroll
        for (int r = 0; r < 4; ++r)
#pragma unroll
            for (int j = 0; j < 4; ++j) {
                se[r][j] = fmaf(ce[j], lev[r], se[r][j]);
                so[r][j] = fmaf(co[j], lov[r], so[r][j]);
            }
#pragma unroll
        for (int j = 0; j < 4; ++j) {
            ce[j] = fmaf(k2[j], co[j], -ce[j]);   // cas((2g+2)*n)
            co[j] = fmaf(k2[j], ce[j], -co[j]);   // cas((2g+3)*n)
        }
    }

#pragma unroll
    for (int r = 0; r < 4; ++r) {
        const size_t row = (size_t)rowbase + rg * 4 + r;
        *reinterpret_cast<float4*>(&out[row * N_FFT + n]) =
            make_float4(se[r][0] + so[r][0], se[r][1] + so[r][1],
                        se[r][2] + so[r][2], se[r][3] + so[r][3]);
        *reinterpret_cast<float4*>(&out[row * N_FFT + HALF + n]) =
            make_float4(se[r][0] - so[r][0], se[r][1] - so[r][1],
                        se[r][2] - so[r][2], se[r][3] - so[r][3]);
    }
}

extern "C" void kernel_launch(void* const* d_in, const int* in_sizes, int n_in,
                              void* d_out, int out_size, void* d_ws, size_t ws_size,
                              hipStream_t stream) {
    const float* x = (const float*)d_in[0];
    const float* w = (const float*)d_in[1];
    float* out = (float*)d_out;
    float* ws  = (float*)d_ws;

    float* castab  = ws;
    float* costab  = ws + 16384;
    float* partial = ws + 32768;
    float* xh      = ws + 8421376;
    float* lowT    = ws + 8486912;

    k_tab<<<64, 256, 0, stream>>>(castab, costab);
    kA<<<1024, 512, 0, stream>>>(x, castab, costab, partial);
    kR<<<1024, 256, 0, stream>>>(partial, xh);
    kB<<<256, 256, 0, stream>>>(xh, w, lowT);
    kC<<<2048, 256, 0, stream>>>(lowT, castab, costab, out);
}

// Round 16
// 67.604 us; speedup vs baseline: 1.7101x; 1.7101x over previous
//
#include <hip/hip_runtime.h>
#include <math.h>

#define N_FFT 16384
#define HALF 8192
#define ROWS 1024    // B*Cin = B*Cout = 16*64
#define KS_A 128     // k-splits of the 8192 half-space
#define KR_A 64      // half-k per kA block
#define CHUNK 32     // half-k per LDS stage
#define NMASK 16383

// ---------------- ws layout (float offsets) ----------------
// castab @0      [16384]   cas(2*pi*i/N)
// costab @16384  [16384]   2*cos(2*pi*i/N)
// partial@32768  [128*65536]
// xh     @8421376 [65536]
// lowT   @8486912 [65536]

__global__ __launch_bounds__(256) void k_tab(float* __restrict__ castab,
                                             float* __restrict__ costab) {
    int i = blockIdx.x * 256 + threadIdx.x;   // grid 64*256 = 16384 exactly
    double ang = 6.283185307179586476925287 * (double)i / (double)N_FFT;
    double c = cos(ang), s = sin(ang);
    castab[i] = (float)(c + s);
    costab[i] = (float)(2.0 * c);
}

// Step A (half-symmetric + cas recurrence):
//   partial[ks][r][c] = sum_{k in split} (x[r][k] +- x[r][k+8192]) * cas(k*m_c*theta)
// grid 1024 = 8 rb * 128 ks; block 512 = 8 waves; wave = 8 m-cols (single
// parity), lane = 2 rows. launch_bounds (512,4): 128-VGPR budget, body uses
// ~64 -> HW can still pack 4 blocks/CU (LDS 32KB allows 5).
__global__ __launch_bounds__(512, 4) void kA(const float* __restrict__ x,
                                             const float* __restrict__ castab,
                                             const float* __restrict__ costab,
                                             float* __restrict__ partial) {
    const int rb = blockIdx.x & 7;
    const int ks = blockIdx.x >> 3;
    const int rowbase = rb << 7;
    const int kbase = ks * KR_A;

    __shared__ float xs[CHUNK][2][128];   // [k][parity][row-swizzled], 32 KB

    const int t   = threadIdx.x;
    const int wq  = __builtin_amdgcn_readfirstlane(t >> 6);  // 0..7, uniform
    const int lam = t & 63;
    const int c0  = wq * 8;               // permuted col octet (single parity)
    const int p   = wq >> 2;              // 0: even m (sum), 1: odd m (diff)
    const int r2  = lam * 2;              // local row pair
    const int mbase = (wq < 4) ? (wq << 4) : (((wq - 4) << 4) + 1);

    float k2[8], cA[8], cB[8];
#pragma unroll
    for (int j = 0; j < 8; ++j) {
        const int m = mbase + 2 * j;
        k2[j] = costab[m];                              // 2*cos(m*theta)
        cB[j] = castab[((kbase - 1) * m) & NMASK];      // cas((kbase-1)*m)
        cA[j] = castab[(kbase * m) & NMASK];            // cas(kbase*m)
    }

    float acc0[8], acc1[8];
#pragma unroll
    for (int j = 0; j < 8; ++j) { acc0[j] = 0.f; acc1[j] = 0.f; }

    for (int ch = 0; ch < KR_A / CHUNK; ++ch) {
        const int k0 = kbase + ch * CHUNK;
        if (ch) __syncthreads();
        // stage halfsums: 128 rows x 32 k
#pragma unroll
        for (int it = 0; it < 2; ++it) {
            const int idx = it * 512 + t;
            const int r = idx >> 3, kq = idx & 7;
            const float4 a4 = *reinterpret_cast<const float4*>(
                &x[(size_t)(rowbase + r) * N_FFT + k0 + kq * 4]);
            const float4 b4 = *reinterpret_cast<const float4*>(
                &x[(size_t)(rowbase + r) * N_FFT + k0 + kq * 4 + HALF]);
            const int rsw = r ^ (kq << 1);
#pragma unroll
            for (int u = 0; u < 4; ++u) {
                const float a = reinterpret_cast<const float*>(&a4)[u];
                const float b = reinterpret_cast<const float*>(&b4)[u];
                xs[kq * 4 + u][0][rsw] = a + b;
                xs[kq * 4 + u][1][rsw] = a - b;
            }
        }
        __syncthreads();

        for (int k = 0; k < CHUNK; k += 2) {
            {   // step k: current = cA; then cB <- c_{k+1}
                const int rd = r2 ^ ((k >> 2) << 1);
                const float2 s2 = *reinterpret_cast<const float2*>(&xs[k][p][rd]);
#pragma unroll
                for (int j = 0; j < 8; ++j) {
                    acc0[j] = fmaf(s2.x, cA[j], acc0[j]);
                    acc1[j] = fmaf(s2.y, cA[j], acc1[j]);
                    cB[j] = fmaf(k2[j], cA[j], -cB[j]);
                }
            }
            {   // step k+1: current = cB; then cA <- c_{k+2}
                const int rd = r2 ^ (((k + 1) >> 2) << 1);
                const float2 s2 = *reinterpret_cast<const float2*>(&xs[k + 1][p][rd]);
#pragma unroll
                for (int j = 0; j < 8; ++j) {
                    acc0[j] = fmaf(s2.x, cB[j], acc0[j]);
                    acc1[j] = fmaf(s2.y, cB[j], acc1[j]);
                    cA[j] = fmaf(k2[j], cB[j], -cA[j]);
                }
            }
        }
    }

#pragma unroll
    for (int i = 0; i < 2; ++i) {
        float* pp = &partial[((size_t)ks << 16) +
                             (size_t)(rowbase + r2 + i) * 64 + c0];
        const float* a = i ? acc1 : acc0;
        *reinterpret_cast<float4*>(pp) =
            make_float4(a[0], a[1], a[2], a[3]);
        *reinterpret_cast<float4*>(pp + 4) =
            make_float4(a[4], a[5], a[6], a[7]);
    }
}

// reduce KS_A=128 partials -> xh (un-permuting columns)
// grid 1024 x 256: block = 64 idx x 4 sp-groups (32 sp each); LDS reduce.
__global__ __launch_bounds__(256) void kR(const float* __restrict__ partial,
                                          float* __restrict__ xh) {
    const int lane = threadIdx.x & 63;
    const int sg   = threadIdx.x >> 6;              // 0..3
    const int idx  = blockIdx.x * 64 + lane;        // 0..65535
    const int sp0  = sg << 5;                       // 32 sp per group

    float a0 = 0.f, a1 = 0.f, a2 = 0.f, a3 = 0.f;
#pragma unroll
    for (int i = 0; i < 32; i += 4) {
        a0 += partial[((size_t)(sp0 + i + 0) << 16) + idx];
        a1 += partial[((size_t)(sp0 + i + 1) << 16) + idx];
        a2 += partial[((size_t)(sp0 + i + 2) << 16) + idx];
        a3 += partial[((size_t)(sp0 + i + 3) << 16) + idx];
    }
    const float s = (a0 + a1) + (a2 + a3);

    __shared__ float red[4][64];
    red[sg][lane] = s;
    __syncthreads();
    if (sg == 0) {
        const float v = (red[0][lane] + red[1][lane]) +
                        (red[2][lane] + red[3][lane]);
        const int r = idx >> 6, c = idx & 63;
        const int m = (c < 32) ? (2 * c) : (2 * (c - 32) + 1);
        xh[(r << 6) + m] = v;
    }
}

// Step B: lowT[m][b*64+o] = (1/N) * sum_i xh[b*64+i][m] * w[(o*64+i)*64+m]
// grid 256 = 16 b * 16 og; block 256 = 4 o * 64 m.
__global__ __launch_bounds__(256) void kB(const float* __restrict__ xh,
                                          const float* __restrict__ w,
                                          float* __restrict__ lowT) {
    const int b  = blockIdx.x >> 4;
    const int og = blockIdx.x & 15;
    const int o  = og * 4 + (threadIdx.x >> 6);
    const int m  = threadIdx.x & 63;
    float a0 = 0.f, a1 = 0.f, a2 = 0.f, a3 = 0.f;
#pragma unroll 4
    for (int i = 0; i < 64; i += 4) {
        a0 = fmaf(xh[(size_t)((b * 64 + i + 0) << 6) + m], w[(size_t)((o * 64 + i + 0) << 6) + m], a0);
        a1 = fmaf(xh[(size_t)((b * 64 + i + 1) << 6) + m], w[(size_t)((o * 64 + i + 1) << 6) + m], a1);
        a2 = fmaf(xh[(size_t)((b * 64 + i + 2) << 6) + m], w[(size_t)((o * 64 + i + 2) << 6) + m], a2);
        a3 = fmaf(xh[(size_t)((b * 64 + i + 3) << 6) + m], w[(size_t)((o * 64 + i + 3) << 6) + m], a3);
    }
    lowT[(size_t)m * ROWS + b * 64 + o] = ((a0 + a1) + (a2 + a3)) * (1.0f / (float)N_FFT);
}

// Step C (half-symmetric + cas recurrence, LDS-broadcast lowT):
//   out[r][n] = Se+So, out[r][n+8192] = Se-So (n<8192)
// grid 2048 = 64 rb * 32 nb; block 256 = 4 waves; tile 16 rows x 256 n.
__global__ __launch_bounds__(256, 4) void kC(const float* __restrict__ lowT,
                                             const float* __restrict__ castab,
                                             const float* __restrict__ costab,
                                             float* __restrict__ out) {
    const int rb = blockIdx.x >> 5;
    const int nb = blockIdx.x & 31;
    const int rowbase = rb << 4;          // 16 rows
    const int n0 = nb << 8;               // 256 half-n

    __shared__ float ls[64][16];          // [m][r], 4 KB

    const int t  = threadIdx.x;
    const int rg = __builtin_amdgcn_readfirstlane(t >> 6);   // 0..3, uniform
    const int nl = t & 63;
    const int n  = n0 + nl * 4;           // lane's 4 n: n..n+3

    // stage lowT tile: 1024 floats
#pragma unroll
    for (int it = 0; it < 4; ++it) {
        const int f = it * 256 + t;
        const int m = f >> 4, r = f & 15;
        ls[m][r] = lowT[((size_t)m << 10) + rowbase + r];
    }
    __syncthreads();

    float k2[4], ce[4], co[4];
#pragma unroll
    for (int j = 0; j < 4; ++j) {
        k2[j] = costab[n + j];
        ce[j] = 1.0f;
        co[j] = castab[n + j];
    }

    float se[4][4], so[4][4];
#pragma unroll
    for (int r = 0; r < 4; ++r)
#pragma unroll
        for (int j = 0; j < 4; ++j) { se[r][j] = 0.f; so[r][j] = 0.f; }

#pragma unroll 4
    for (int g = 0; g < 32; ++g) {
        const float4 le = *reinterpret_cast<const float4*>(&ls[2 * g][rg * 4]);
        const float4 lo = *reinterpret_cast<const float4*>(&ls[2 * g + 1][rg * 4]);
        const float lev[4] = {le.x, le.y, le.z, le.w};
        const float lov[4] = {lo.x, lo.y, lo.z, lo.w};
#pragma unroll
        for (int r = 0; r < 4; ++r)
#pragma unroll
            for (int j = 0; j < 4; ++j) {
                se[r][j] = fmaf(ce[j], lev[r], se[r][j]);
                so[r][j] = fmaf(co[j], lov[r], so[r][j]);
            }
#pragma unroll
        for (int j = 0; j < 4; ++j) {
            ce[j] = fmaf(k2[j], co[j], -ce[j]);   // cas((2g+2)*n)
            co[j] = fmaf(k2[j], ce[j], -co[j]);   // cas((2g+3)*n)
        }
    }

#pragma unroll
    for (int r = 0; r < 4; ++r) {
        const size_t row = (size_t)rowbase + rg * 4 + r;
        *reinterpret_cast<float4*>(&out[row * N_FFT + n]) =
            make_float4(se[r][0] + so[r][0], se[r][1] + so[r][1],
                        se[r][2] + so[r][2], se[r][3] + so[r][3]);
        *reinterpret_cast<float4*>(&out[row * N_FFT + HALF + n]) =
            make_float4(se[r][0] - so[r][0], se[r][1] - so[r][1],
                        se[r][2] - so[r][2], se[r][3] - so[r][3]);
    }
}

extern "C" void kernel_launch(void* const* d_in, const int* in_sizes, int n_in,
                              void* d_out, int out_size, void* d_ws, size_t ws_size,
                              hipStream_t stream) {
    const float* x = (const float*)d_in[0];
    const float* w = (const float*)d_in[1];
    float* out = (float*)d_out;
    float* ws  = (float*)d_ws;

    float* castab  = ws;
    float* costab  = ws + 16384;
    float* partial = ws + 32768;
    float* xh      = ws + 8421376;
    float* lowT    = ws + 8486912;

    k_tab<<<64, 256, 0, stream>>>(castab, costab);
    kA<<<1024, 512, 0, stream>>>(x, castab, costab, partial);
    kR<<<1024, 256, 0, stream>>>(partial, xh);
    kB<<<256, 256, 0, stream>>>(xh, w, lowT);
    kC<<<2048, 256, 0, stream>>>(lowT, castab, costab, out);
}

// Round 17
// 66.088 us; speedup vs baseline: 1.7493x; 1.0229x over previous
//
#include <hip/hip_runtime.h>
#include <math.h>

#define N_FFT 16384
#define HALF 8192
#define ROWS 1024    // B*Cin = B*Cout = 16*64
#define KS_A 64      // k-splits of the 8192 half-space
#define KR_A 128     // half-k per kA block
#define CHUNK 32     // half-k per LDS stage
#define NMASK 16383

// ---------------- ws layout (float offsets) ----------------
// castab @0      [16384]   cas(2*pi*i/N)
// costab @16384  [16384]   2*cos(2*pi*i/N)
// partial@32768  [64*65536]
// xh     @4227072 [65536]
// lowT   @4292608 [65536]

#define GLOAD_LDS16(g, l)                                          \
    __builtin_amdgcn_global_load_lds(                              \
        (const __attribute__((address_space(1))) void*)(g),        \
        (__attribute__((address_space(3))) void*)(l), 16, 0, 0)

__global__ __launch_bounds__(256) void k_tab(float* __restrict__ castab,
                                             float* __restrict__ costab) {
    int i = blockIdx.x * 256 + threadIdx.x;   // grid 64*256 = 16384 exactly
    double ang = 6.283185307179586476925287 * (double)i / (double)N_FFT;
    double c = cos(ang), s = sin(ang);
    castab[i] = (float)(c + s);
    costab[i] = (float)(2.0 * c);
}

// Step A (half-symmetric + cas recurrence + global_load_lds double-buffer):
//   partial[ks][r][c] = sum_{k in split} (x[r][k] +- x[r][k+8192]) * cas(k*m)
// grid 512 = 8 rb * 64 ks; block 512 = 8 waves; wave = 8 m-cols (single
// parity), lane = rows (lam, lam+64). Raw x halves DMA'd to LDS with
// source-side XOR swizzle (granule q^(r&7)); +-combine done at read time
// (sign is per-wave constant). Loads for chunk c+1 issued BEFORE compute
// of chunk c; the vmcnt(0) the compiler emits at __syncthreads lands after
// ~2.6us of compute -> HBM latency hidden. One barrier per chunk.
__global__ __launch_bounds__(512, 4) void kA(const float* __restrict__ x,
                                             const float* __restrict__ castab,
                                             const float* __restrict__ costab,
                                             float* __restrict__ partial) {
    const int rb = blockIdx.x & 7;
    const int ks = blockIdx.x >> 3;
    const int rowbase = rb << 7;
    const int kbase = ks * KR_A;

    __shared__ float xsA[2][128 * 32];   // raw first-half,  16 KB per buf
    __shared__ float xsB[2][128 * 32];   // raw second-half, 16 KB per buf

    const int t   = threadIdx.x;
    const int wq  = __builtin_amdgcn_readfirstlane(t >> 6);  // 0..7, uniform
    const int lam = t & 63;
    const int c0  = wq * 8;               // permuted col octet (single parity)
    const float sgn = (wq >> 2) ? -1.0f : 1.0f;   // even m: +, odd m: -
    const int mbase = (wq < 4) ? (wq << 4) : (((wq - 4) << 4) + 1);

    const int rsw  = lam & 7;             // read-side swizzle key (same for lam+64)
    const int off0base = lam << 5;        // row lam
    // row lam+64 sits +64*32 floats higher

    float k2[8], cA[8], cB[8];
#pragma unroll
    for (int j = 0; j < 8; ++j) {
        const int m = mbase + 2 * j;
        k2[j] = costab[m];                              // 2*cos(m*theta)
        cB[j] = castab[((kbase - 1) * m) & NMASK];      // cas((kbase-1)*m)
        cA[j] = castab[(kbase * m) & NMASK];            // cas(kbase*m)
    }

    float acc0[8], acc1[8];
#pragma unroll
    for (int j = 0; j < 8; ++j) { acc0[j] = 0.f; acc1[j] = 0.f; }

    // staging geometry: granule flat = it*512 + t ; r = flat>>3 ; q = flat&7.
    // LDS is LINEAR in flat (dest = wave-uniform base + lane*16); the SOURCE
    // k-offset is pre-swizzled: physical k = K0 + ((q ^ (r&7))*4).
#define ISSUE(K0, BUF)                                                        \
    _Pragma("unroll")                                                         \
    for (int it = 0; it < 2; ++it) {                                          \
        const int flat = it * 512 + t;                                        \
        const int r = flat >> 3, q = flat & 7;                                \
        const int kq = ((q ^ (r & 7)) << 2);                                  \
        const float* sa = &x[(size_t)(rowbase + r) * N_FFT + (K0) + kq];      \
        const int wbase = (it * 512 + wq * 64) << 2;                          \
        GLOAD_LDS16(sa, &xsA[BUF][wbase]);                                    \
        GLOAD_LDS16(sa + HALF, &xsB[BUF][wbase]);                             \
    }

    ISSUE(kbase, 0);
    __syncthreads();   // drains chunk-0 DMA (compiler emits vmcnt(0))

    for (int ch = 0; ch < KR_A / CHUNK; ++ch) {
        const int buf = ch & 1;
        if (ch + 1 < KR_A / CHUNK) { ISSUE(kbase + (ch + 1) * CHUNK, buf ^ 1); }

#pragma unroll
        for (int k = 0; k < CHUNK; k += 2) {
            const int off0 = off0base + (((k >> 2) ^ rsw) << 2) + (k & 3);
            const int off1 = off0 + 64 * 32;
            const float2 a0 = *reinterpret_cast<const float2*>(&xsA[buf][off0]);
            const float2 a1 = *reinterpret_cast<const float2*>(&xsA[buf][off1]);
            const float2 b0 = *reinterpret_cast<const float2*>(&xsB[buf][off0]);
            const float2 b1 = *reinterpret_cast<const float2*>(&xsB[buf][off1]);
            const float x00 = fmaf(sgn, b0.x, a0.x);   // row lam,    k
            const float x01 = fmaf(sgn, b0.y, a0.y);   // row lam,    k+1
            const float x10 = fmaf(sgn, b1.x, a1.x);   // row lam+64, k
            const float x11 = fmaf(sgn, b1.y, a1.y);   // row lam+64, k+1
            {   // step k: current = cA; then cB <- c_{k+1}
#pragma unroll
                for (int j = 0; j < 8; ++j) {
                    acc0[j] = fmaf(x00, cA[j], acc0[j]);
                    acc1[j] = fmaf(x10, cA[j], acc1[j]);
                    cB[j] = fmaf(k2[j], cA[j], -cB[j]);
                }
            }
            {   // step k+1: current = cB; then cA <- c_{k+2}
#pragma unroll
                for (int j = 0; j < 8; ++j) {
                    acc0[j] = fmaf(x01, cB[j], acc0[j]);
                    acc1[j] = fmaf(x11, cB[j], acc1[j]);
                    cA[j] = fmaf(k2[j], cB[j], -cA[j]);
                }
            }
        }
        __syncthreads();   // DMA for next chunk drained + buf free to overwrite
    }
#undef ISSUE

    {
        float* pp0 = &partial[((size_t)ks << 16) +
                              (size_t)(rowbase + lam) * 64 + c0];
        float* pp1 = pp0 + (size_t)64 * 64;   // row lam+64
        *reinterpret_cast<float4*>(pp0) =
            make_float4(acc0[0], acc0[1], acc0[2], acc0[3]);
        *reinterpret_cast<float4*>(pp0 + 4) =
            make_float4(acc0[4], acc0[5], acc0[6], acc0[7]);
        *reinterpret_cast<float4*>(pp1) =
            make_float4(acc1[0], acc1[1], acc1[2], acc1[3]);
        *reinterpret_cast<float4*>(pp1 + 4) =
            make_float4(acc1[4], acc1[5], acc1[6], acc1[7]);
    }
}

// reduce KS_A partials -> xh (un-permuting columns); grid 256 x 256
__global__ __launch_bounds__(256) void kR(const float* __restrict__ partial,
                                          float* __restrict__ xh) {
    const int idx = blockIdx.x * 256 + threadIdx.x;   // 0..65535
    const int r = idx >> 6, c = idx & 63;
    const int m = (c < 32) ? (2 * c) : (2 * (c - 32) + 1);
    float a0 = 0.f, a1 = 0.f, a2 = 0.f, a3 = 0.f;
#pragma unroll 4
    for (int sp = 0; sp < KS_A; sp += 4) {
        a0 += partial[((size_t)(sp + 0) << 16) + idx];
        a1 += partial[((size_t)(sp + 1) << 16) + idx];
        a2 += partial[((size_t)(sp + 2) << 16) + idx];
        a3 += partial[((size_t)(sp + 3) << 16) + idx];
    }
    xh[(r << 6) + m] = (a0 + a1) + (a2 + a3);
}

// Step B: lowT[m][b*64+o] = (1/N) * sum_i xh[b*64+i][m] * w[(o*64+i)*64+m]
// grid 256 = 16 b * 16 og; block 256 = 4 o * 64 m.
__global__ __launch_bounds__(256) void kB(const float* __restrict__ xh,
                                          const float* __restrict__ w,
                                          float* __restrict__ lowT) {
    const int b  = blockIdx.x >> 4;
    const int og = blockIdx.x & 15;
    const int o  = og * 4 + (threadIdx.x >> 6);
    const int m  = threadIdx.x & 63;
    float a0 = 0.f, a1 = 0.f, a2 = 0.f, a3 = 0.f;
#pragma unroll 4
    for (int i = 0; i < 64; i += 4) {
        a0 = fmaf(xh[(size_t)((b * 64 + i + 0) << 6) + m], w[(size_t)((o * 64 + i + 0) << 6) + m], a0);
        a1 = fmaf(xh[(size_t)((b * 64 + i + 1) << 6) + m], w[(size_t)((o * 64 + i + 1) << 6) + m], a1);
        a2 = fmaf(xh[(size_t)((b * 64 + i + 2) << 6) + m], w[(size_t)((o * 64 + i + 2) << 6) + m], a2);
        a3 = fmaf(xh[(size_t)((b * 64 + i + 3) << 6) + m], w[(size_t)((o * 64 + i + 3) << 6) + m], a3);
    }
    lowT[(size_t)m * ROWS + b * 64 + o] = ((a0 + a1) + (a2 + a3)) * (1.0f / (float)N_FFT);
}

// Step C (half-symmetric + cas recurrence, LDS-broadcast lowT):
//   out[r][n] = Se+So, out[r][n+8192] = Se-So (n<8192)
// grid 2048 = 64 rb * 32 nb; block 256 = 4 waves; tile 16 rows x 256 n.
__global__ __launch_bounds__(256, 4) void kC(const float* __restrict__ lowT,
                                             const float* __restrict__ castab,
                                             const float* __restrict__ costab,
                                             float* __restrict__ out) {
    const int rb = blockIdx.x >> 5;
    const int nb = blockIdx.x & 31;
    const int rowbase = rb << 4;          // 16 rows
    const int n0 = nb << 8;               // 256 half-n

    __shared__ float ls[64][16];          // [m][r], 4 KB

    const int t  = threadIdx.x;
    const int rg = __builtin_amdgcn_readfirstlane(t >> 6);   // 0..3, uniform
    const int nl = t & 63;
    const int n  = n0 + nl * 4;           // lane's 4 n: n..n+3

    // stage lowT tile: 1024 floats
#pragma unroll
    for (int it = 0; it < 4; ++it) {
        const int f = it * 256 + t;
        const int m = f >> 4, r = f & 15;
        ls[m][r] = lowT[((size_t)m << 10) + rowbase + r];
    }
    __syncthreads();

    float k2[4], ce[4], co[4];
#pragma unroll
    for (int j = 0; j < 4; ++j) {
        k2[j] = costab[n + j];
        ce[j] = 1.0f;
        co[j] = castab[n + j];
    }

    float se[4][4], so[4][4];
#pragma unroll
    for (int r = 0; r < 4; ++r)
#pragma unroll
        for (int j = 0; j < 4; ++j) { se[r][j] = 0.f; so[r][j] = 0.f; }

#pragma unroll 4
    for (int g = 0; g < 32; ++g) {
        const float4 le = *reinterpret_cast<const float4*>(&ls[2 * g][rg * 4]);
        const float4 lo = *reinterpret_cast<const float4*>(&ls[2 * g + 1][rg * 4]);
        const float lev[4] = {le.x, le.y, le.z, le.w};
        const float lov[4] = {lo.x, lo.y, lo.z, lo.w};
#pragma unroll
        for (int r = 0; r < 4; ++r)
#pragma unroll
            for (int j = 0; j < 4; ++j) {
                se[r][j] = fmaf(ce[j], lev[r], se[r][j]);
                so[r][j] = fmaf(co[j], lov[r], so[r][j]);
            }
#pragma unroll
        for (int j = 0; j < 4; ++j) {
            ce[j] = fmaf(k2[j], co[j], -ce[j]);   // cas((2g+2)*n)
            co[j] = fmaf(k2[j], ce[j], -co[j]);   // cas((2g+3)*n)
        }
    }

#pragma unroll
    for (int r = 0; r < 4; ++r) {
        const size_t row = (size_t)rowbase + rg * 4 + r;
        *reinterpret_cast<float4*>(&out[row * N_FFT + n]) =
            make_float4(se[r][0] + so[r][0], se[r][1] + so[r][1],
                        se[r][2] + so[r][2], se[r][3] + so[r][3]);
        *reinterpret_cast<float4*>(&out[row * N_FFT + HALF + n]) =
            make_float4(se[r][0] - so[r][0], se[r][1] - so[r][1],
                        se[r][2] - so[r][2], se[r][3] - so[r][3]);
    }
}

extern "C" void kernel_launch(void* const* d_in, const int* in_sizes, int n_in,
                              void* d_out, int out_size, void* d_ws, size_t ws_size,
                              hipStream_t stream) {
    const float* x = (const float*)d_in[0];
    const float* w = (const float*)d_in[1];
    float* out = (float*)d_out;
    float* ws  = (float*)d_ws;

    float* castab  = ws;
    float* costab  = ws + 16384;
    float* partial = ws + 32768;
    float* xh      = ws + 4227072;
    float* lowT    = ws + 4292608;

    k_tab<<<64, 256, 0, stream>>>(castab, costab);
    kA<<<512, 512, 0, stream>>>(x, castab, costab, partial);
    kR<<<256, 256, 0, stream>>>(partial, xh);
    kB<<<256, 256, 0, stream>>>(xh, w, lowT);
    kC<<<2048, 256, 0, stream>>>(lowT, castab, costab, out);
}

// Round 18
// 63.348 us; speedup vs baseline: 1.8249x; 1.0432x over previous
//
#include <hip/hip_runtime.h>
#include <math.h>

#define N_FFT 16384
#define HALF 8192
#define ROWS 1024    // B*Cin = B*Cout = 16*64
#define KS_A 64      // k-splits of the 8192 half-space
#define KR_A 128     // half-k per kA block
#define CHUNK 32     // half-k per LDS stage
#define NMASK 16383

// ---------------- ws layout (float offsets) ----------------
// castab @0      [16384]   cas(2*pi*i/N)
// costab @16384  [16384]   2*cos(2*pi*i/N)
// partial@32768  [64*65536]
// xh     @4227072 [65536]
// lowT   @4292608 [65536]

__global__ __launch_bounds__(256) void k_tab(float* __restrict__ castab,
                                             float* __restrict__ costab) {
    int i = blockIdx.x * 256 + threadIdx.x;   // grid 64*256 = 16384 exactly
    double ang = 6.283185307179586476925287 * (double)i / (double)N_FFT;
    double c = cos(ang), s = sin(ang);
    castab[i] = (float)(c + s);
    costab[i] = (float)(2.0 * c);
}

// Step A (half-symmetric + cas recurrence + LDS-read software pipeline):
//   partial[ks][r][c] = sum_{k in split} (x[r][k] +- x[r][k+8192]) * cas(k*m_c*theta)
// grid 512 = 8 rb * 64 ks; block 512 = 8 waves; wave = 8 m-cols (single parity),
// lane = 2 rows. Inner loop reads prefetched 2 pair-iterations (~192 cyc) ahead
// to hide the ~120-cyc LDS latency within each wave.
__global__ __launch_bounds__(512, 4) void kA(const float* __restrict__ x,
                                             const float* __restrict__ castab,
                                             const float* __restrict__ costab,
                                             float* __restrict__ partial) {
    const int rb = blockIdx.x & 7;
    const int ks = blockIdx.x >> 3;
    const int rowbase = rb << 7;
    const int kbase = ks * KR_A;

    __shared__ float xs[CHUNK][2][128];   // [k][parity][row-swizzled], 32 KB

    const int t   = threadIdx.x;
    const int wq  = __builtin_amdgcn_readfirstlane(t >> 6);  // 0..7, uniform
    const int lam = t & 63;
    const int c0  = wq * 8;               // permuted col octet (single parity)
    const int p   = wq >> 2;              // 0: even m (sum), 1: odd m (diff)
    const int r2  = lam * 2;              // local row pair
    const int mbase = (wq < 4) ? (wq << 4) : (((wq - 4) << 4) + 1);

    float k2[8], cA[8], cB[8];
#pragma unroll
    for (int j = 0; j < 8; ++j) {
        const int m = mbase + 2 * j;
        k2[j] = costab[m];                              // 2*cos(m*theta)
        cB[j] = castab[((kbase - 1) * m) & NMASK];      // cas((kbase-1)*m)
        cA[j] = castab[(kbase * m) & NMASK];            // cas(kbase*m)
    }

    float acc0[8], acc1[8];
#pragma unroll
    for (int j = 0; j < 8; ++j) { acc0[j] = 0.f; acc1[j] = 0.f; }

#define LDX(K) (*reinterpret_cast<const float2*>(                              \
        &xs[(K)][p][r2 ^ ((((K) >> 2)) << 1)]))

    for (int ch = 0; ch < KR_A / CHUNK; ++ch) {
        const int k0 = kbase + ch * CHUNK;
        if (ch) __syncthreads();
        // stage halfsums: 128 rows x 32 k
#pragma unroll
        for (int it = 0; it < 2; ++it) {
            const int idx = it * 512 + t;
            const int r = idx >> 3, kq = idx & 7;
            const float4 a4 = *reinterpret_cast<const float4*>(
                &x[(size_t)(rowbase + r) * N_FFT + k0 + kq * 4]);
            const float4 b4 = *reinterpret_cast<const float4*>(
                &x[(size_t)(rowbase + r) * N_FFT + k0 + kq * 4 + HALF]);
            const int rsw = r ^ (kq << 1);
#pragma unroll
            for (int u = 0; u < 4; ++u) {
                const float a = reinterpret_cast<const float*>(&a4)[u];
                const float b = reinterpret_cast<const float*>(&b4)[u];
                xs[kq * 4 + u][0][rsw] = a + b;
                xs[kq * 4 + u][1][rsw] = a - b;
            }
        }
        __syncthreads();

        // software-pipelined compute: reads 2 pair-iterations ahead
        float2 s0 = LDX(0), s1 = LDX(1), s2v = LDX(2), s3v = LDX(3);
#pragma unroll
        for (int k = 0; k < CHUNK; k += 2) {
            float2 n0 = make_float2(0.f, 0.f), n1 = make_float2(0.f, 0.f);
            if (k + 5 < CHUNK) { n0 = LDX(k + 4); n1 = LDX(k + 5); }
            {   // step k: current = cA; then cB <- c_{k+1}
#pragma unroll
                for (int j = 0; j < 8; ++j) {
                    acc0[j] = fmaf(s0.x, cA[j], acc0[j]);
                    acc1[j] = fmaf(s0.y, cA[j], acc1[j]);
                    cB[j] = fmaf(k2[j], cA[j], -cB[j]);
                }
            }
            {   // step k+1: current = cB; then cA <- c_{k+2}
#pragma unroll
                for (int j = 0; j < 8; ++j) {
                    acc0[j] = fmaf(s1.x, cB[j], acc0[j]);
                    acc1[j] = fmaf(s1.y, cB[j], acc1[j]);
                    cA[j] = fmaf(k2[j], cB[j], -cA[j]);
                }
            }
            s0 = s2v; s1 = s3v; s2v = n0; s3v = n1;
        }
    }
#undef LDX

#pragma unroll
    for (int i = 0; i < 2; ++i) {
        float* pp = &partial[((size_t)ks << 16) +
                             (size_t)(rowbase + r2 + i) * 64 + c0];
        const float* a = i ? acc1 : acc0;
        *reinterpret_cast<float4*>(pp) =
            make_float4(a[0], a[1], a[2], a[3]);
        *reinterpret_cast<float4*>(pp + 4) =
            make_float4(a[4], a[5], a[6], a[7]);
    }
}

// reduce KS_A partials -> xh (un-permuting columns); grid 256 x 256
__global__ __launch_bounds__(256) void kR(const float* __restrict__ partial,
                                          float* __restrict__ xh) {
    const int idx = blockIdx.x * 256 + threadIdx.x;   // 0..65535
    const int r = idx >> 6, c = idx & 63;
    const int m = (c < 32) ? (2 * c) : (2 * (c - 32) + 1);
    float a0 = 0.f, a1 = 0.f, a2 = 0.f, a3 = 0.f;
#pragma unroll 4
    for (int sp = 0; sp < KS_A; sp += 4) {
        a0 += partial[((size_t)(sp + 0) << 16) + idx];
        a1 += partial[((size_t)(sp + 1) << 16) + idx];
        a2 += partial[((size_t)(sp + 2) << 16) + idx];
        a3 += partial[((size_t)(sp + 3) << 16) + idx];
    }
    xh[(r << 6) + m] = (a0 + a1) + (a2 + a3);
}

// Step B: lowT[m][b*64+o] = (1/N) * sum_i xh[b*64+i][m] * w[(o*64+i)*64+m]
// grid 256 = 16 b * 16 og; block 256 = 4 o * 64 m.
__global__ __launch_bounds__(256) void kB(const float* __restrict__ xh,
                                          const float* __restrict__ w,
                                          float* __restrict__ lowT) {
    const int b  = blockIdx.x >> 4;
    const int og = blockIdx.x & 15;
    const int o  = og * 4 + (threadIdx.x >> 6);
    const int m  = threadIdx.x & 63;
    float a0 = 0.f, a1 = 0.f, a2 = 0.f, a3 = 0.f;
#pragma unroll 4
    for (int i = 0; i < 64; i += 4) {
        a0 = fmaf(xh[(size_t)((b * 64 + i + 0) << 6) + m], w[(size_t)((o * 64 + i + 0) << 6) + m], a0);
        a1 = fmaf(xh[(size_t)((b * 64 + i + 1) << 6) + m], w[(size_t)((o * 64 + i + 1) << 6) + m], a1);
        a2 = fmaf(xh[(size_t)((b * 64 + i + 2) << 6) + m], w[(size_t)((o * 64 + i + 2) << 6) + m], a2);
        a3 = fmaf(xh[(size_t)((b * 64 + i + 3) << 6) + m], w[(size_t)((o * 64 + i + 3) << 6) + m], a3);
    }
    lowT[(size_t)m * ROWS + b * 64 + o] = ((a0 + a1) + (a2 + a3)) * (1.0f / (float)N_FFT);
}

// Step C (half-symmetric + cas recurrence, LDS-broadcast lowT):
//   out[r][n] = Se+So, out[r][n+8192] = Se-So (n<8192)
// grid 2048 = 64 rb * 32 nb; block 256 = 4 waves; tile 16 rows x 256 n.
__global__ __launch_bounds__(256, 4) void kC(const float* __restrict__ lowT,
                                             const float* __restrict__ castab,
                                             const float* __restrict__ costab,
                                             float* __restrict__ out) {
    const int rb = blockIdx.x >> 5;
    const int nb = blockIdx.x & 31;
    const int rowbase = rb << 4;          // 16 rows
    const int n0 = nb << 8;               // 256 half-n

    __shared__ float ls[64][16];          // [m][r], 4 KB

    const int t  = threadIdx.x;
    const int rg = __builtin_amdgcn_readfirstlane(t >> 6);   // 0..3, uniform
    const int nl = t & 63;
    const int n  = n0 + nl * 4;           // lane's 4 n: n..n+3

    // stage lowT tile: 1024 floats
#pragma unroll
    for (int it = 0; it < 4; ++it) {
        const int f = it * 256 + t;
        const int m = f >> 4, r = f & 15;
        ls[m][r] = lowT[((size_t)m << 10) + rowbase + r];
    }
    __syncthreads();

    float k2[4], ce[4], co[4];
#pragma unroll
    for (int j = 0; j < 4; ++j) {
        k2[j] = costab[n + j];
        ce[j] = 1.0f;
        co[j] = castab[n + j];
    }

    float se[4][4], so[4][4];
#pragma unroll
    for (int r = 0; r < 4; ++r)
#pragma unroll
        for (int j = 0; j < 4; ++j) { se[r][j] = 0.f; so[r][j] = 0.f; }

#pragma unroll 4
    for (int g = 0; g < 32; ++g) {
        const float4 le = *reinterpret_cast<const float4*>(&ls[2 * g][rg * 4]);
        const float4 lo = *reinterpret_cast<const float4*>(&ls[2 * g + 1][rg * 4]);
        const float lev[4] = {le.x, le.y, le.z, le.w};
        const float lov[4] = {lo.x, lo.y, lo.z, lo.w};
#pragma unroll
        for (int r = 0; r < 4; ++r)
#pragma unroll
            for (int j = 0; j < 4; ++j) {
                se[r][j] = fmaf(ce[j], lev[r], se[r][j]);
                so[r][j] = fmaf(co[j], lov[r], so[r][j]);
            }
#pragma unroll
        for (int j = 0; j < 4; ++j) {
            ce[j] = fmaf(k2[j], co[j], -ce[j]);   // cas((2g+2)*n)
            co[j] = fmaf(k2[j], ce[j], -co[j]);   // cas((2g+3)*n)
        }
    }

#pragma unroll
    for (int r = 0; r < 4; ++r) {
        const size_t row = (size_t)rowbase + rg * 4 + r;
        *reinterpret_cast<float4*>(&out[row * N_FFT + n]) =
            make_float4(se[r][0] + so[r][0], se[r][1] + so[r][1],
                        se[r][2] + so[r][2], se[r][3] + so[r][3]);
        *reinterpret_cast<float4*>(&out[row * N_FFT + HALF + n]) =
            make_float4(se[r][0] - so[r][0], se[r][1] - so[r][1],
                        se[r][2] - so[r][2], se[r][3] - so[r][3]);
    }
}

extern "C" void kernel_launch(void* const* d_in, const int* in_sizes, int n_in,
                              void* d_out, int out_size, void* d_ws, size_t ws_size,
                              hipStream_t stream) {
    const float* x = (const float*)d_in[0];
    const float* w = (const float*)d_in[1];
    float* out = (float*)d_out;
    float* ws  = (float*)d_ws;

    float* castab  = ws;
    float* costab  = ws + 16384;
    float* partial = ws + 32768;
    float* xh      = ws + 4227072;
    float* lowT    = ws + 4292608;

    k_tab<<<64, 256, 0, stream>>>(castab, costab);
    kA<<<512, 512, 0, stream>>>(x, castab, costab, partial);
    kR<<<256, 256, 0, stream>>>(partial, xh);
    kB<<<256, 256, 0, stream>>>(xh, w, lowT);
    kC<<<2048, 256, 0, stream>>>(lowT, castab, costab, out);
}

// Round 19
// 62.545 us; speedup vs baseline: 1.8484x; 1.0129x over previous
//
#include <hip/hip_runtime.h>
#include <math.h>

#define N_FFT 16384
#define HALF 8192
#define ROWS 1024    // B*Cin = B*Cout = 16*64
#define KS_A 64      // k-splits of the 8192 half-space
#define KR_A 128     // half-k per kA block
#define CHUNK 32     // half-k per LDS stage
#define NMASK 16383

// ---------------- ws layout (float offsets) ----------------
// castab @0      [16384]   cas(2*pi*i/N)
// costab @16384  [16384]   2*cos(2*pi*i/N)
// partial@32768  [64*65536]
// xh     @4227072 [65536]
// lowT   @4292608 [65536]

__global__ __launch_bounds__(256) void k_tab(float* __restrict__ castab,
                                             float* __restrict__ costab) {
    int i = blockIdx.x * 256 + threadIdx.x;   // grid 64*256 = 16384 exactly
    double ang = 6.283185307179586476925287 * (double)i / (double)N_FFT;
    double c = cos(ang), s = sin(ang);
    castab[i] = (float)(c + s);
    costab[i] = (float)(2.0 * c);
}

// Step A (half-symmetric + cas recurrence + k-pair-interleaved LDS):
//   partial[ks][r][c] = sum_{k in split} (x[r][k] +- x[r][k+8192]) * cas(k*m_c)
// grid 512 = 8 rb * 64 ks; block 512 = 8 waves; wave = 8 m-cols (single
// parity), lane = 2 rows. LDS layout [kpair][parity][row'][kparity]:
//   write: 4 ds_write_b64 per granule (was 8 b32), row' = r ^ (kq<<2)
//   read : 1 ds_read_b128 per k-pair (was 2 b64) — both rows x both k's.
// Halves LDS instruction issue on both sides; FMA count unchanged.
__global__ __launch_bounds__(512, 4) void kA(const float* __restrict__ x,
                                             const float* __restrict__ castab,
                                             const float* __restrict__ costab,
                                             float* __restrict__ partial) {
    const int rb = blockIdx.x & 7;
    const int ks = blockIdx.x >> 3;
    const int rowbase = rb << 7;
    const int kbase = ks * KR_A;

    __shared__ float xs[CHUNK / 2][2][128][2];   // 32 KB

    const int t   = threadIdx.x;
    const int wq  = __builtin_amdgcn_readfirstlane(t >> 6);  // 0..7, uniform
    const int lam = t & 63;
    const int c0  = wq * 8;               // permuted col octet (single parity)
    const int p   = wq >> 2;              // 0: even m (sum), 1: odd m (diff)
    const int r2  = lam * 2;              // local row pair
    const int mbase = (wq < 4) ? (wq << 4) : (((wq - 4) << 4) + 1);

    float k2[8], cA[8], cB[8];
#pragma unroll
    for (int j = 0; j < 8; ++j) {
        const int m = mbase + 2 * j;
        k2[j] = costab[m];                              // 2*cos(m*theta)
        cB[j] = castab[((kbase - 1) * m) & NMASK];      // cas((kbase-1)*m)
        cA[j] = castab[(kbase * m) & NMASK];            // cas(kbase*m)
    }

    float acc0[8], acc1[8];
#pragma unroll
    for (int j = 0; j < 8; ++j) { acc0[j] = 0.f; acc1[j] = 0.f; }

    // read: physical rows (r2^key, r2^key+1); key = (kp>>1)<<2 is wave-uniform
#define LDQ(KP) (*reinterpret_cast<const float4*>(                             \
        &xs[(KP)][p][r2 ^ (((KP) >> 1) << 2)][0]))

    for (int ch = 0; ch < KR_A / CHUNK; ++ch) {
        const int k0 = kbase + ch * CHUNK;
        if (ch) __syncthreads();
        // stage halfsums: 128 rows x 32 k, pair-interleaved
#pragma unroll
        for (int it = 0; it < 2; ++it) {
            const int flat = it * 512 + t;
            const int r = flat >> 3, kq = flat & 7;
            const float4 a4 = *reinterpret_cast<const float4*>(
                &x[(size_t)(rowbase + r) * N_FFT + k0 + kq * 4]);
            const float4 b4 = *reinterpret_cast<const float4*>(
                &x[(size_t)(rowbase + r) * N_FFT + k0 + kq * 4 + HALF]);
            const int rp = r ^ (kq << 2);
            *reinterpret_cast<float2*>(&xs[kq * 2][0][rp][0]) =
                make_float2(a4.x + b4.x, a4.y + b4.y);
            *reinterpret_cast<float2*>(&xs[kq * 2][1][rp][0]) =
                make_float2(a4.x - b4.x, a4.y - b4.y);
            *reinterpret_cast<float2*>(&xs[kq * 2 + 1][0][rp][0]) =
                make_float2(a4.z + b4.z, a4.w + b4.w);
            *reinterpret_cast<float2*>(&xs[kq * 2 + 1][1][rp][0]) =
                make_float2(a4.z - b4.z, a4.w - b4.w);
        }
        __syncthreads();

        // compute: 1 b128 per k-pair, prefetched 2 pairs ahead
        float4 qa = LDQ(0), qb = LDQ(1);
#pragma unroll
        for (int kp = 0; kp < CHUNK / 2; ++kp) {
            float4 qn = make_float4(0.f, 0.f, 0.f, 0.f);
            if (kp + 2 < CHUNK / 2) { qn = LDQ(kp + 2); }
            // qa = {r2@k, r2@k+1, r2+1@k, r2+1@k+1}, k = 2*kp
            {   // step k: current = cA; then cB <- c_{k+1}
#pragma unroll
                for (int j = 0; j < 8; ++j) {
                    acc0[j] = fmaf(qa.x, cA[j], acc0[j]);
                    acc1[j] = fmaf(qa.z, cA[j], acc1[j]);
                    cB[j] = fmaf(k2[j], cA[j], -cB[j]);
                }
            }
            {   // step k+1: current = cB; then cA <- c_{k+2}
#pragma unroll
                for (int j = 0; j < 8; ++j) {
                    acc0[j] = fmaf(qa.y, cB[j], acc0[j]);
                    acc1[j] = fmaf(qa.w, cB[j], acc1[j]);
                    cA[j] = fmaf(k2[j], cB[j], -cA[j]);
                }
            }
            qa = qb; qb = qn;
        }
    }
#undef LDQ

#pragma unroll
    for (int i = 0; i < 2; ++i) {
        float* pp = &partial[((size_t)ks << 16) +
                             (size_t)(rowbase + r2 + i) * 64 + c0];
        const float* a = i ? acc1 : acc0;
        *reinterpret_cast<float4*>(pp) =
            make_float4(a[0], a[1], a[2], a[3]);
        *reinterpret_cast<float4*>(pp + 4) =
            make_float4(a[4], a[5], a[6], a[7]);
    }
}

// reduce KS_A partials -> xh (un-permuting columns); grid 256 x 256
__global__ __launch_bounds__(256) void kR(const float* __restrict__ partial,
                                          float* __restrict__ xh) {
    const int idx = blockIdx.x * 256 + threadIdx.x;   // 0..65535
    const int r = idx >> 6, c = idx & 63;
    const int m = (c < 32) ? (2 * c) : (2 * (c - 32) + 1);
    float a0 = 0.f, a1 = 0.f, a2 = 0.f, a3 = 0.f;
#pragma unroll 4
    for (int sp = 0; sp < KS_A; sp += 4) {
        a0 += partial[((size_t)(sp + 0) << 16) + idx];
        a1 += partial[((size_t)(sp + 1) << 16) + idx];
        a2 += partial[((size_t)(sp + 2) << 16) + idx];
        a3 += partial[((size_t)(sp + 3) << 16) + idx];
    }
    xh[(r << 6) + m] = (a0 + a1) + (a2 + a3);
}

// Step B: lowT[m][b*64+o] = (1/N) * sum_i xh[b*64+i][m] * w[(o*64+i)*64+m]
// grid 256 = 16 b * 16 og; block 256 = 4 o * 64 m.
__global__ __launch_bounds__(256) void kB(const float* __restrict__ xh,
                                          const float* __restrict__ w,
                                          float* __restrict__ lowT) {
    const int b  = blockIdx.x >> 4;
    const int og = blockIdx.x & 15;
    const int o  = og * 4 + (threadIdx.x >> 6);
    const int m  = threadIdx.x & 63;
    float a0 = 0.f, a1 = 0.f, a2 = 0.f, a3 = 0.f;
#pragma unroll 4
    for (int i = 0; i < 64; i += 4) {
        a0 = fmaf(xh[(size_t)((b * 64 + i + 0) << 6) + m], w[(size_t)((o * 64 + i + 0) << 6) + m], a0);
        a1 = fmaf(xh[(size_t)((b * 64 + i + 1) << 6) + m], w[(size_t)((o * 64 + i + 1) << 6) + m], a1);
        a2 = fmaf(xh[(size_t)((b * 64 + i + 2) << 6) + m], w[(size_t)((o * 64 + i + 2) << 6) + m], a2);
        a3 = fmaf(xh[(size_t)((b * 64 + i + 3) << 6) + m], w[(size_t)((o * 64 + i + 3) << 6) + m], a3);
    }
    lowT[(size_t)m * ROWS + b * 64 + o] = ((a0 + a1) + (a2 + a3)) * (1.0f / (float)N_FFT);
}

// Step C (half-symmetric + cas recurrence, LDS-broadcast lowT):
//   out[r][n] = Se+So, out[r][n+8192] = Se-So (n<8192)
// grid 2048 = 64 rb * 32 nb; block 256 = 4 waves; tile 16 rows x 256 n.
__global__ __launch_bounds__(256, 4) void kC(const float* __restrict__ lowT,
                                             const float* __restrict__ castab,
                                             const float* __restrict__ costab,
                                             float* __restrict__ out) {
    const int rb = blockIdx.x >> 5;
    const int nb = blockIdx.x & 31;
    const int rowbase = rb << 4;          // 16 rows
    const int n0 = nb << 8;               // 256 half-n

    __shared__ float ls[64][16];          // [m][r], 4 KB

    const int t  = threadIdx.x;
    const int rg = __builtin_amdgcn_readfirstlane(t >> 6);   // 0..3, uniform
    const int nl = t & 63;
    const int n  = n0 + nl * 4;           // lane's 4 n: n..n+3

    // stage lowT tile: 1024 floats
#pragma unroll
    for (int it = 0; it < 4; ++it) {
        const int f = it * 256 + t;
        const int m = f >> 4, r = f & 15;
        ls[m][r] = lowT[((size_t)m << 10) + rowbase + r];
    }
    __syncthreads();

    float k2[4], ce[4], co[4];
#pragma unroll
    for (int j = 0; j < 4; ++j) {
        k2[j] = costab[n + j];
        ce[j] = 1.0f;
        co[j] = castab[n + j];
    }

    float se[4][4], so[4][4];
#pragma unroll
    for (int r = 0; r < 4; ++r)
#pragma unroll
        for (int j = 0; j < 4; ++j) { se[r][j] = 0.f; so[r][j] = 0.f; }

#pragma unroll 4
    for (int g = 0; g < 32; ++g) {
        const float4 le = *reinterpret_cast<const float4*>(&ls[2 * g][rg * 4]);
        const float4 lo = *reinterpret_cast<const float4*>(&ls[2 * g + 1][rg * 4]);
        const float lev[4] = {le.x, le.y, le.z, le.w};
        const float lov[4] = {lo.x, lo.y, lo.z, lo.w};
#pragma unroll
        for (int r = 0; r < 4; ++r)
#pragma unroll
            for (int j = 0; j < 4; ++j) {
                se[r][j] = fmaf(ce[j], lev[r], se[r][j]);
                so[r][j] = fmaf(co[j], lov[r], so[r][j]);
            }
#pragma unroll
        for (int j = 0; j < 4; ++j) {
            ce[j] = fmaf(k2[j], co[j], -ce[j]);   // cas((2g+2)*n)
            co[j] = fmaf(k2[j], ce[j], -co[j]);   // cas((2g+3)*n)
        }
    }

#pragma unroll
    for (int r = 0; r < 4; ++r) {
        const size_t row = (size_t)rowbase + rg * 4 + r;
        *reinterpret_cast<float4*>(&out[row * N_FFT + n]) =
            make_float4(se[r][0] + so[r][0], se[r][1] + so[r][1],
                        se[r][2] + so[r][2], se[r][3] + so[r][3]);
        *reinterpret_cast<float4*>(&out[row * N_FFT + HALF + n]) =
            make_float4(se[r][0] - so[r][0], se[r][1] - so[r][1],
                        se[r][2] - so[r][2], se[r][3] - so[r][3]);
    }
}

extern "C" void kernel_launch(void* const* d_in, const int* in_sizes, int n_in,
                              void* d_out, int out_size, void* d_ws, size_t ws_size,
                              hipStream_t stream) {
    const float* x = (const float*)d_in[0];
    const float* w = (const float*)d_in[1];
    float* out = (float*)d_out;
    float* ws  = (float*)d_ws;

    float* castab  = ws;
    float* costab  = ws + 16384;
    float* partial = ws + 32768;
    float* xh      = ws + 4227072;
    float* lowT    = ws + 4292608;

    k_tab<<<64, 256, 0, stream>>>(castab, costab);
    kA<<<512, 512, 0, stream>>>(x, castab, costab, partial);
    kR<<<256, 256, 0, stream>>>(partial, xh);
    kB<<<256, 256, 0, stream>>>(xh, w, lowT);
    kC<<<2048, 256, 0, stream>>>(lowT, castab, costab, out);
}